// Round 1
// baseline (146.465 us; speedup 1.0000x reference)
//
#include <hip/hip_runtime.h>
#include <hip/hip_bf16.h>

#define B_    4
#define C_    192
#define N_    8192
#define K_    16
#define O_    192
#define TWOC_ 384

typedef __attribute__((ext_vector_type(8))) short short8;
typedef __attribute__((ext_vector_type(4))) float floatx4;

static __device__ __forceinline__ float bf2f(unsigned short u) {
    union { unsigned int i; float f; } v; v.i = ((unsigned int)u) << 16; return v.f;
}
static __device__ __forceinline__ unsigned short f2bf(float f) {
    union { float f; unsigned int i; } v; v.f = f;
    unsigned int x = v.i;
    return (unsigned short)((x + 0x7FFFu + ((x >> 16) & 1u)) >> 16);
}

// ---------------- K0: W fp32 -> bf16 ----------------
__global__ __launch_bounds__(256) void k_convert_w(const float* __restrict__ W,
                                                   unsigned short* __restrict__ Wb) {
    int i = blockIdx.x * 256 + threadIdx.x;
    if (i < O_ * TWOC_) Wb[i] = f2bf(W[i]);
}

// ---------------- K1: transpose x[B,C,N] fp32 -> y[B,N,384] bf16 (cols 0..191) ----------------
__global__ __launch_bounds__(256) void k_transpose(const float* __restrict__ x,
                                                   unsigned short* __restrict__ yb) {
    __shared__ float tile[32][33];
    int b  = blockIdx.z;
    int c0 = blockIdx.y * 32;
    int n0 = blockIdx.x * 32;
    int tx = threadIdx.x, ty = threadIdx.y;  // 32 x 8
    const float* xp = x + ((size_t)b * C_ + c0) * N_ + n0;
#pragma unroll
    for (int i = 0; i < 4; i++) {
        int r = ty + 8 * i;                  // c_local
        tile[r][tx] = xp[(size_t)r * N_ + tx];
    }
    __syncthreads();
    unsigned short* yp = yb + ((size_t)b * N_ + n0) * TWOC_ + c0;
#pragma unroll
    for (int i = 0; i < 4; i++) {
        int r = ty + 8 * i;                  // n_local
        yp[(size_t)r * TWOC_ + tx] = f2bf(tile[tx][r]);
    }
}

// ---------------- K2: max-relative gather, writes y[...,192..383] ----------------
// One wave per node; 3 channels per lane (lane, lane+64, lane+128).
__global__ __launch_bounds__(256) void k_maxrel(unsigned short* __restrict__ yb,
                                                const int* __restrict__ eidx) {
    int b    = blockIdx.y;
    int wave = threadIdx.x >> 6;
    int lane = threadIdx.x & 63;
    int n    = blockIdx.x * 4 + wave;

    __shared__ int sidx[4][32];
    if (lane < 32) {
        const int* e = eidx + ((size_t)b * N_ + n) * K_;
        int v;
        if (lane < 16) v = e[lane];                                   // j = edge[0]
        else           v = e[(size_t)B_ * N_ * K_ + (lane - 16)];     // i = edge[1]
        sidx[wave][lane] = v;
    }
    __syncthreads();

    const unsigned short* base = yb + (size_t)b * N_ * TWOC_;
    float m0 = -INFINITY, m1 = -INFINITY, m2 = -INFINITY;
#pragma unroll
    for (int k = 0; k < K_; k++) {
        int j = sidx[wave][k];
        int i = sidx[wave][16 + k];
        const unsigned short* pj = base + (size_t)j * TWOC_;
        const unsigned short* pi = base + (size_t)i * TWOC_;
        float d0 = bf2f(pj[lane])        - bf2f(pi[lane]);
        float d1 = bf2f(pj[lane + 64])   - bf2f(pi[lane + 64]);
        float d2 = bf2f(pj[lane + 128])  - bf2f(pi[lane + 128]);
        m0 = fmaxf(m0, d0);
        m1 = fmaxf(m1, d1);
        m2 = fmaxf(m2, d2);
    }
    unsigned short* w = yb + ((size_t)b * N_ + n) * TWOC_ + C_;
    w[lane]       = f2bf(m0);
    w[lane + 64]  = f2bf(m1);
    w[lane + 128] = f2bf(m2);
}

// ---------------- K3: out[b,o,n] = ReLU(W[o,:] . y[b,n,:] + bias[o]) via MFMA ----------------
// One wave per 64o x 64n tile. A = W rows (K-contig), B = Y rows (K-contig) -> NT GEMM.
// Fragment: lane holds [row = lane&15][k = (lane>>4)*8 + j], 16B contiguous loads.
// D: row(=o) = (lane>>4)*4 + reg, col(=n) = lane&15.
__global__ __launch_bounds__(64) void k_gemm(const unsigned short* __restrict__ Wb,
                                             const unsigned short* __restrict__ yb,
                                             const float* __restrict__ bias,
                                             float* __restrict__ out) {
    int b    = blockIdx.z;
    int ob   = blockIdx.y;   // 0..2  (64 o each)
    int nb   = blockIdx.x;   // 0..127 (64 n each)
    int lane = threadIdx.x;
    int m16  = lane & 15;
    int quad = lane >> 4;

    const unsigned short* wbase = Wb + (size_t)(ob * 64 + m16) * TWOC_ + quad * 8;
    const unsigned short* ybase = yb + ((size_t)b * N_ + nb * 64 + m16) * TWOC_ + quad * 8;

    floatx4 acc[4][4];
#pragma unroll
    for (int i = 0; i < 4; i++)
#pragma unroll
        for (int j = 0; j < 4; j++) acc[i][j] = (floatx4){0.f, 0.f, 0.f, 0.f};

#pragma unroll 2
    for (int kt = 0; kt < 12; kt++) {
        short8 af[4], bfr[4];
#pragma unroll
        for (int t = 0; t < 4; t++)
            af[t] = *(const short8*)(wbase + (size_t)(t * 16) * TWOC_ + kt * 32);
#pragma unroll
        for (int t = 0; t < 4; t++)
            bfr[t] = *(const short8*)(ybase + (size_t)(t * 16) * TWOC_ + kt * 32);
#pragma unroll
        for (int i = 0; i < 4; i++)
#pragma unroll
            for (int j = 0; j < 4; j++)
                acc[i][j] = __builtin_amdgcn_mfma_f32_16x16x32_bf16(af[i], bfr[j], acc[i][j], 0, 0, 0);
    }

#pragma unroll
    for (int i = 0; i < 4; i++) {
#pragma unroll
        for (int r = 0; r < 4; r++) {
            int o = ob * 64 + i * 16 + quad * 4 + r;
            float bv = bias[o];
#pragma unroll
            for (int j = 0; j < 4; j++) {
                int n = nb * 64 + j * 16 + m16;
                float v = acc[i][j][r] + bv;
                out[((size_t)b * O_ + o) * N_ + n] = fmaxf(v, 0.f);
            }
        }
    }
}

extern "C" void kernel_launch(void* const* d_in, const int* in_sizes, int n_in,
                              void* d_out, int out_size, void* d_ws, size_t ws_size,
                              hipStream_t stream) {
    const float* x    = (const float*)d_in[0];
    // d_in[1] (x_0) unused by forward
    const int*   eidx = (const int*)d_in[2];
    const float* W    = (const float*)d_in[3];
    const float* bias = (const float*)d_in[4];
    float*       out  = (float*)d_out;

    unsigned short* Wb = (unsigned short*)d_ws;                       // 192*384*2 = 147456 B
    unsigned short* yb = (unsigned short*)((char*)d_ws + 147456);     // 4*8192*384*2 = 24 MiB

    k_convert_w<<<dim3((O_ * TWOC_ + 255) / 256), dim3(256), 0, stream>>>(W, Wb);
    k_transpose<<<dim3(N_ / 32, C_ / 32, B_), dim3(32, 8), 0, stream>>>(x, yb);
    k_maxrel<<<dim3(N_ / 4, B_), dim3(256), 0, stream>>>(yb, eidx);
    k_gemm<<<dim3(N_ / 64, O_ / 64, B_), dim3(64), 0, stream>>>(Wb, yb, bias, out);
}

// Round 2
// 136.036 us; speedup vs baseline: 1.0767x; 1.0767x over previous
//
#include <hip/hip_runtime.h>

#define B_    4
#define C_    192
#define N_    8192
#define K_    16
#define O_    192
#define TWOC_ 384

typedef __attribute__((ext_vector_type(8))) short short8;
typedef __attribute__((ext_vector_type(4))) short short4v;
typedef __attribute__((ext_vector_type(2))) unsigned int uint2v;
typedef __attribute__((ext_vector_type(4))) float floatx4;

static __device__ __forceinline__ float bf2f(unsigned int u16) {
    union { unsigned int i; float f; } v; v.i = u16 << 16; return v.f;
}
static __device__ __forceinline__ unsigned short f2bf(float f) {
    union { float f; unsigned int i; } v; v.f = f;
    unsigned int x = v.i;
    return (unsigned short)((x + 0x7FFFu + ((x >> 16) & 1u)) >> 16);
}

// ---------------- K0: W fp32 -> bf16 ----------------
__global__ __launch_bounds__(256) void k_convert_w(const float* __restrict__ W,
                                                   unsigned short* __restrict__ Wb) {
    int i = blockIdx.x * 256 + threadIdx.x;
    if (i < O_ * TWOC_) Wb[i] = f2bf(W[i]);
}

// ---------------- K1: x[B,C,N] fp32 -> xt[B,N,192] bf16 (compact) ----------------
// XCD swizzle: batch b -> XCDs {2b, 2b+1} (blockIdx % 8 round-robin heuristic).
__global__ __launch_bounds__(256) void k_transpose(const float* __restrict__ x,
                                                   unsigned short* __restrict__ xt) {
    __shared__ float tile[32][33];
    int bid  = blockIdx.x;               // 6144 blocks
    int xcd  = bid & 7;
    int b    = xcd >> 1;
    int half = xcd & 1;
    int slot = bid >> 3;                 // 0..767
    int ct   = slot >> 7;                // 0..5
    int nt   = half * 128 + (slot & 127);// 0..255
    int c0 = ct * 32, n0 = nt * 32;
    int tid = threadIdx.x;

    // load 32c x 32n fp32, transpose into LDS [n][c]
    int cc  = tid >> 3;                  // 0..31
    int nn4 = (tid & 7) * 4;             // 0,4,..,28
    const float* xp = x + ((size_t)b * C_ + c0 + cc) * N_ + n0 + nn4;
    float4 v = *(const float4*)xp;
    tile[nn4 + 0][cc] = v.x;
    tile[nn4 + 1][cc] = v.y;
    tile[nn4 + 2][cc] = v.z;
    tile[nn4 + 3][cc] = v.w;
    __syncthreads();

    // write bf16 pairs: xt[b, n0+row, c0 + 2*ch2 .. +1]
#pragma unroll
    for (int i = 0; i < 2; i++) {
        int id  = i * 256 + tid;         // 0..511
        int row = id >> 4;               // 0..31
        int ch2 = id & 15;               // 0..15 (ushort2 chunk)
        float a = tile[row][ch2 * 2];
        float c = tile[row][ch2 * 2 + 1];
        unsigned int pack = (unsigned int)f2bf(a) | ((unsigned int)f2bf(c) << 16);
        *(unsigned int*)(xt + ((size_t)b * N_ + n0 + row) * C_ + c0 + ch2 * 2) = pack;
    }
}

// ---------------- K2: fused max-rel gather + 1x1 conv (MFMA) ----------------
// One block = 64 nodes of one batch. 256 threads = 4 waves.
// LDS y-tile[64][384] bf16: cols 0..191 = own xs rows, cols 192..383 = rel.
// Then 4 waves compute out[192 o][64 n] = ReLU(W . y + b) via 16x16x32 MFMA.
__global__ __launch_bounds__(256) void k_fused(const unsigned short* __restrict__ xt,
                                               const int* __restrict__ eidx,
                                               const unsigned short* __restrict__ Wb,
                                               const float* __restrict__ bias,
                                               float* __restrict__ out) {
    __shared__ unsigned short ytile[64][TWOC_];   // 48 KiB
    __shared__ int sidx[64][33];                  // 8.25 KiB (padded: conflict-free bcast)

    int bid  = blockIdx.x;               // 512 blocks
    int xcd  = bid & 7;
    int b    = xcd >> 1;
    int slot = bid >> 3;                 // 0..63
    int n0   = ((xcd & 1) * 64 + slot) * 64;

    int tid  = threadIdx.x;
    int wave = tid >> 6;
    int lane = tid & 63;

    // ---- load edge indices: sidx[node][0..15]=j (e0), [16..31]=i (e1) ----
    const int* e0 = eidx + ((size_t)b * N_ + n0) * K_;
    const int* e1 = e0 + (size_t)B_ * N_ * K_;
#pragma unroll
    for (int i = 0; i < 4; i++) {
        int id   = i * 256 + tid;        // 0..1023
        int node = id >> 4, k = id & 15;
        sidx[node][k]      = e0[id];
        sidx[node][16 + k] = e1[id];
    }

    // ---- stage A: own xs rows -> ytile[:, 0..191] ----
    const unsigned short* xrow = xt + ((size_t)b * N_ + n0) * C_;
#pragma unroll
    for (int i = 0; i < 6; i++) {
        int id = i * 256 + tid;          // 0..1535
        int row = id / 24, chunk = id % 24;
        short8 v = *(const short8*)(xrow + (size_t)row * C_ + chunk * 8);
        *(short8*)&ytile[row][chunk * 8] = v;
    }
    __syncthreads();

    // ---- stage B: gather max-rel -> ytile[:, 192..383] ----
    // wave handles 16 nodes, processed 4 at a time (lane>>4 = node subgroup),
    // lane&15 covers 4 channels per t-chunk (3 chunks of 64 ch).
    {
        int g  = lane >> 4;
        int l4 = lane & 15;
        const unsigned short* xbase = xt + (size_t)b * N_ * C_;
#pragma unroll
        for (int bb = 0; bb < 4; bb++) {
            int node = wave * 16 + bb * 4 + g;
            float m[3][4];
#pragma unroll
            for (int t = 0; t < 3; t++)
#pragma unroll
                for (int c = 0; c < 4; c++) m[t][c] = -INFINITY;
#pragma unroll
            for (int k = 0; k < K_; k++) {
                int jn = sidx[node][k];
                int in = sidx[node][16 + k];
                const unsigned short* pj = xbase + (size_t)jn * C_ + l4 * 4;
                const unsigned short* pi = xbase + (size_t)in * C_ + l4 * 4;
#pragma unroll
                for (int t = 0; t < 3; t++) {
                    uint2v vj = *(const uint2v*)(pj + t * 64);
                    uint2v vi = *(const uint2v*)(pi + t * 64);
                    m[t][0] = fmaxf(m[t][0], bf2f(vj.x & 0xffffu) - bf2f(vi.x & 0xffffu));
                    m[t][1] = fmaxf(m[t][1], bf2f(vj.x >> 16)     - bf2f(vi.x >> 16));
                    m[t][2] = fmaxf(m[t][2], bf2f(vj.y & 0xffffu) - bf2f(vi.y & 0xffffu));
                    m[t][3] = fmaxf(m[t][3], bf2f(vj.y >> 16)     - bf2f(vi.y >> 16));
                }
            }
#pragma unroll
            for (int t = 0; t < 3; t++) {
                short4v s;
                s.x = (short)f2bf(m[t][0]);
                s.y = (short)f2bf(m[t][1]);
                s.z = (short)f2bf(m[t][2]);
                s.w = (short)f2bf(m[t][3]);
                *(short4v*)&ytile[node][C_ + t * 64 + l4 * 4] = s;
            }
        }
    }
    __syncthreads();

    // ---- GEMM: wave w covers o rows [w*48, w*48+48), all 64 n ----
    int m16  = lane & 15;
    int quad = lane >> 4;
    const unsigned short* wbase = Wb + (size_t)(wave * 48 + m16) * TWOC_ + quad * 8;

    floatx4 acc[3][4];
#pragma unroll
    for (int i = 0; i < 3; i++)
#pragma unroll
        for (int j = 0; j < 4; j++) acc[i][j] = (floatx4){0.f, 0.f, 0.f, 0.f};

#pragma unroll 2
    for (int kt = 0; kt < 12; kt++) {
        short8 wf[3], yf[4];
#pragma unroll
        for (int i = 0; i < 3; i++)
            wf[i] = *(const short8*)(wbase + (size_t)(i * 16) * TWOC_ + kt * 32);
#pragma unroll
        for (int j = 0; j < 4; j++)
            yf[j] = *(const short8*)&ytile[j * 16 + m16][kt * 32 + quad * 8];
#pragma unroll
        for (int i = 0; i < 3; i++)
#pragma unroll
            for (int j = 0; j < 4; j++)
                acc[i][j] = __builtin_amdgcn_mfma_f32_16x16x32_bf16(wf[i], yf[j], acc[i][j], 0, 0, 0);
    }

#pragma unroll
    for (int i = 0; i < 3; i++) {
#pragma unroll
        for (int r = 0; r < 4; r++) {
            int o = wave * 48 + i * 16 + quad * 4 + r;
            float bv = bias[o];
#pragma unroll
            for (int j = 0; j < 4; j++) {
                int n = n0 + j * 16 + m16;
                out[((size_t)b * O_ + o) * N_ + n] = fmaxf(acc[i][j][r] + bv, 0.f);
            }
        }
    }
}

extern "C" void kernel_launch(void* const* d_in, const int* in_sizes, int n_in,
                              void* d_out, int out_size, void* d_ws, size_t ws_size,
                              hipStream_t stream) {
    const float* x    = (const float*)d_in[0];
    const int*   eidx = (const int*)d_in[2];
    const float* W    = (const float*)d_in[3];
    const float* bias = (const float*)d_in[4];
    float*       out  = (float*)d_out;

    unsigned short* Wb = (unsigned short*)d_ws;                     // 147456 B
    unsigned short* xt = (unsigned short*)((char*)d_ws + 147456);   // 4*8192*192*2 = 12.6 MB

    k_convert_w<<<dim3((O_ * TWOC_ + 255) / 256), dim3(256), 0, stream>>>(W, Wb);
    k_transpose<<<dim3(6144), dim3(256), 0, stream>>>(x, xt);
    k_fused<<<dim3(512), dim3(256), 0, stream>>>(xt, eidx, Wb, bias, out);
}